// Round 5
// baseline (748.275 us; speedup 1.0000x reference)
//
#include <hip/hip_runtime.h>
#include <hip/hip_fp16.h>

#define N_PTS 2097152
#define GRID_ 512
#define F_FEAT 32
#define HW (GRID_ * GRID_)
#define HWF ((size_t)HW * F_FEAT) // elements per transposed plane = 8388608

#define NBINS 64
#define BIN_SHIFT 3   // 512 rows / 64 bins = 8 rows per bin
#define BIN_CAP 40960 // mean 32768 per bin, +25% (~40 sigma) headroom

typedef float f32x4 __attribute__((ext_vector_type(4)));

// ---------------------------------------------------------------------------
// Kernel 0: scale[f] = sum_k core[k][f]   (core is (16, 32))
// ---------------------------------------------------------------------------
__global__ void td_scale_kernel(const float* __restrict__ core,
                                float* __restrict__ scale) {
    int f = threadIdx.x; // 32 threads
    float s = 0.0f;
#pragma unroll
    for (int k = 0; k < 16; ++k) s += core[k * F_FEAT + f];
    scale[f] = s;
}

// ---------------------------------------------------------------------------
// Kernel 1: transpose (F, H, W) f32 -> (H, W, F) fp16. Plane 0 folds scale in.
// ---------------------------------------------------------------------------
__global__ void td_transpose_kernel(const float* __restrict__ pxy,
                                    const float* __restrict__ pyz,
                                    const float* __restrict__ pxz,
                                    const float* __restrict__ scale,
                                    __half* __restrict__ wsh) {
    __shared__ float tile[32][33]; // +1 pad: conflict-free
    const int plane = blockIdx.z;
    const float* src = (plane == 0) ? pxy : ((plane == 1) ? pyz : pxz);
    __half* dst = wsh + (size_t)plane * HWF;
    const int y = blockIdx.y;
    const int x0 = blockIdx.x * 32;

    for (int i = threadIdx.y; i < 32; i += 8) {
        tile[i][threadIdx.x] =
            src[(size_t)i * HW + (size_t)y * GRID_ + x0 + threadIdx.x];
    }
    __syncthreads();
    const float sc = (plane == 0) ? scale[threadIdx.x] : 1.0f;
    for (int i = threadIdx.y; i < 32; i += 8) {
        dst[((size_t)(y * GRID_ + x0 + i)) * F_FEAT + threadIdx.x] =
            __float2half(tile[threadIdx.x][i] * sc);
    }
}

// ---------------------------------------------------------------------------
// Kernel 2: zero the bin cursors (3 * 64 ints). Must run every launch.
// ---------------------------------------------------------------------------
__global__ void td_zero_kernel(int* __restrict__ cursor) {
    cursor[threadIdx.x] = 0; // 192 threads
}

// ---------------------------------------------------------------------------
// Kernel 3: bin points by y-stripe. Two-level atomic append (LDS then global).
// Record = (pid bitcast, cx, cy, 0). Order within bin is irrelevant.
// ---------------------------------------------------------------------------
__global__ __launch_bounds__(256) void td_bin_kernel(
    const float2* __restrict__ coords, int* __restrict__ cursor,
    float4* __restrict__ binned) {
    __shared__ int lhist[NBINS];
    __shared__ int lbase[NBINS];
    const int pl = blockIdx.y;
    const int p = blockIdx.x * 256 + threadIdx.x;
    if (threadIdx.x < NBINS) lhist[threadIdx.x] = 0;
    __syncthreads();

    const float2 c = coords[(size_t)pl * N_PTS + p];
    const float yf = (c.y + 1.0f) * 0.5f * (float)(GRID_ - 1);
    int y0 = (int)floorf(yf);
    y0 = min(max(y0, 0), GRID_ - 1);
    const int bin = y0 >> BIN_SHIFT;
    const int lslot = atomicAdd(&lhist[bin], 1);
    __syncthreads();

    if (threadIdx.x < NBINS) {
        const int cnt = lhist[threadIdx.x];
        lbase[threadIdx.x] =
            (cnt > 0) ? atomicAdd(&cursor[pl * NBINS + threadIdx.x], cnt) : 0;
    }
    __syncthreads();

    const int slot = lbase[bin] + lslot;
    if (slot < BIN_CAP) {
        float4 rec;
        rec.x = __int_as_float(p);
        rec.y = c.x;
        rec.z = c.y;
        rec.w = 0.0f;
        binned[((size_t)pl * NBINS + bin) * BIN_CAP + slot] = rec;
    }
}

// ---------------------------------------------------------------------------
// Kernel 4: per-plane sampling in bin order. 4 lanes per point (fq = feature
// octet, 16B per corner). Stripe (512KB) is L2-resident -> gathers hit L2.
// Writes 32 fp16 features NT to feat[pl][pid].
// ---------------------------------------------------------------------------
__global__ __launch_bounds__(256) void td_sample_plane_kernel(
    const float4* __restrict__ binned, const int* __restrict__ cursor,
    const f32x4* __restrict__ ws4, f32x4* __restrict__ feat) {
    const int g = blockIdx.x * 256 + threadIdx.x;
    const int slot = g >> 2;
    const int fq = g & 3;
    const int pl = blockIdx.y;
    const int bin = slot / BIN_CAP;
    const int i = slot - bin * BIN_CAP;
    const int cnt = min(cursor[pl * NBINS + bin], BIN_CAP);
    if (i >= cnt) return;

    const float4 rec = binned[(size_t)pl * NBINS * BIN_CAP + slot];
    const int pid = __float_as_int(rec.x);

    const float xf = (rec.y + 1.0f) * 0.5f * (float)(GRID_ - 1);
    const float yf = (rec.z + 1.0f) * 0.5f * (float)(GRID_ - 1);
    const float x0f = floorf(xf);
    const float y0f = floorf(yf);
    const float wx = xf - x0f;
    const float wy = yf - y0f;
    int x0 = (int)x0f;
    int y0 = (int)y0f;
    x0 = min(max(x0, 0), GRID_ - 1);
    y0 = min(max(y0, 0), GRID_ - 1);
    const int x1 = min(x0 + 1, GRID_ - 1);
    const int y1 = min(y0 + 1, GRID_ - 1);

    const f32x4* tp = ws4 + (size_t)pl * (HWF / 8);
    const f32x4 r00 = tp[(size_t)(y0 * GRID_ + x0) * 4 + fq];
    const f32x4 r01 = tp[(size_t)(y0 * GRID_ + x1) * 4 + fq];
    const f32x4 r10 = tp[(size_t)(y1 * GRID_ + x0) * 4 + fq];
    const f32x4 r11 = tp[(size_t)(y1 * GRID_ + x1) * 4 + fq];

    const float w00 = (1.0f - wx) * (1.0f - wy);
    const float w01 = wx * (1.0f - wy);
    const float w10 = (1.0f - wx) * wy;
    const float w11 = wx * wy;

    const half2* h00 = reinterpret_cast<const half2*>(&r00);
    const half2* h01 = reinterpret_cast<const half2*>(&r01);
    const half2* h10 = reinterpret_cast<const half2*>(&r10);
    const half2* h11 = reinterpret_cast<const half2*>(&r11);

    union {
        f32x4 v;
        half2 h[4];
    } u;
#pragma unroll
    for (int j = 0; j < 4; ++j) {
        const float2 f00 = __half22float2(h00[j]);
        const float2 f01 = __half22float2(h01[j]);
        const float2 f10 = __half22float2(h10[j]);
        const float2 f11 = __half22float2(h11[j]);
        const float sa = f00.x * w00 + f01.x * w01 + f10.x * w10 + f11.x * w11;
        const float sb = f00.y * w00 + f01.y * w01 + f10.y * w10 + f11.y * w11;
        u.h[j] = __floats2half2_rn(sa, sb);
    }
    __builtin_nontemporal_store(u.v, &feat[((size_t)pl * N_PTS + pid) * 4 + fq]);
}

// ---------------------------------------------------------------------------
// Kernel 5: combine. Streaming read of 3 fp16 feature buffers (p-order),
// multiply in f32, NT store f32 out.
// ---------------------------------------------------------------------------
__global__ __launch_bounds__(256) void td_combine_kernel(
    const f32x4* __restrict__ feat, f32x4* __restrict__ out) {
    const size_t g = (size_t)blockIdx.x * 256 + threadIdx.x; // N*4 threads
    union U {
        f32x4 v;
        half2 h[4];
    };
    U a, b, c;
    a.v = feat[g];
    b.v = feat[(size_t)N_PTS * 4 + g];
    c.v = feat[(size_t)2 * N_PTS * 4 + g];

    float r[8];
#pragma unroll
    for (int j = 0; j < 4; ++j) {
        const float2 fa = __half22float2(a.h[j]);
        const float2 fb = __half22float2(b.h[j]);
        const float2 fc = __half22float2(c.h[j]);
        r[2 * j] = fa.x * fb.x * fc.x;
        r[2 * j + 1] = fa.y * fb.y * fc.y;
    }
    f32x4 o0, o1;
    o0.x = r[0]; o0.y = r[1]; o0.z = r[2]; o0.w = r[3];
    o1.x = r[4]; o1.y = r[5]; o1.z = r[6]; o1.w = r[7];
    const size_t ob = ((g >> 2) * 8) + (g & 3) * 2;
    __builtin_nontemporal_store(o0, &out[ob]);
    __builtin_nontemporal_store(o1, &out[ob + 1]);
}

// ---------------------------------------------------------------------------
// Tier-2 (R4 path): fused random-gather sampling (needs only fp16 planes).
// ---------------------------------------------------------------------------
__global__ __launch_bounds__(256) void td_sample_kernel(
    const float2* __restrict__ coords, const f32x4* __restrict__ ws4,
    f32x4* __restrict__ out) {
    const int tid = blockIdx.x * 256 + threadIdx.x;
    const int p = tid >> 2;
    const int fq = tid & 3;

    const float2 c0 = coords[p];
    const float2 c1 = coords[N_PTS + p];
    const float2 c2 = coords[2 * N_PTS + p];

    size_t idx[3][4];
    float w[3][4];
    const float2 cc[3] = {c0, c1, c2};
#pragma unroll
    for (int pl = 0; pl < 3; ++pl) {
        const float xf = (cc[pl].x + 1.0f) * 0.5f * (float)(GRID_ - 1);
        const float yf = (cc[pl].y + 1.0f) * 0.5f * (float)(GRID_ - 1);
        const float x0f = floorf(xf);
        const float y0f = floorf(yf);
        const float wx = xf - x0f;
        const float wy = yf - y0f;
        int x0 = (int)x0f;
        int y0 = (int)y0f;
        x0 = min(max(x0, 0), GRID_ - 1);
        y0 = min(max(y0, 0), GRID_ - 1);
        const int x1 = min(x0 + 1, GRID_ - 1);
        const int y1 = min(y0 + 1, GRID_ - 1);
        const size_t base = (size_t)pl * (HWF / 8);
        idx[pl][0] = base + (size_t)(y0 * GRID_ + x0) * 4 + fq;
        idx[pl][1] = base + (size_t)(y0 * GRID_ + x1) * 4 + fq;
        idx[pl][2] = base + (size_t)(y1 * GRID_ + x0) * 4 + fq;
        idx[pl][3] = base + (size_t)(y1 * GRID_ + x1) * 4 + fq;
        w[pl][0] = (1.0f - wx) * (1.0f - wy);
        w[pl][1] = wx * (1.0f - wy);
        w[pl][2] = (1.0f - wx) * wy;
        w[pl][3] = wx * wy;
    }

    f32x4 v[3][4];
#pragma unroll
    for (int pl = 0; pl < 3; ++pl)
#pragma unroll
        for (int cnr = 0; cnr < 4; ++cnr) v[pl][cnr] = ws4[idx[pl][cnr]];

    float prod[8];
#pragma unroll
    for (int j = 0; j < 8; ++j) prod[j] = 1.0f;

#pragma unroll
    for (int pl = 0; pl < 3; ++pl) {
        const half2* h0 = reinterpret_cast<const half2*>(&v[pl][0]);
        const half2* h1 = reinterpret_cast<const half2*>(&v[pl][1]);
        const half2* h2 = reinterpret_cast<const half2*>(&v[pl][2]);
        const half2* h3 = reinterpret_cast<const half2*>(&v[pl][3]);
#pragma unroll
        for (int j = 0; j < 4; ++j) {
            const float2 f00 = __half22float2(h0[j]);
            const float2 f01 = __half22float2(h1[j]);
            const float2 f10 = __half22float2(h2[j]);
            const float2 f11 = __half22float2(h3[j]);
            prod[2 * j] *= f00.x * w[pl][0] + f01.x * w[pl][1] +
                           f10.x * w[pl][2] + f11.x * w[pl][3];
            prod[2 * j + 1] *= f00.y * w[pl][0] + f01.y * w[pl][1] +
                               f10.y * w[pl][2] + f11.y * w[pl][3];
        }
    }

    f32x4 o0, o1;
    o0.x = prod[0]; o0.y = prod[1]; o0.z = prod[2]; o0.w = prod[3];
    o1.x = prod[4]; o1.y = prod[5]; o1.z = prod[6]; o1.w = prod[7];
    __builtin_nontemporal_store(o0, &out[(size_t)tid * 2]);
    __builtin_nontemporal_store(o1, &out[(size_t)tid * 2 + 1]);
}

// ---------------------------------------------------------------------------
// Tier-3 fallback: direct strided gather from (F,H,W), f32, no workspace.
// ---------------------------------------------------------------------------
__global__ __launch_bounds__(256) void td_fallback_kernel(
    const float* __restrict__ coords, const float* __restrict__ pxy,
    const float* __restrict__ pyz, const float* __restrict__ pxz,
    const float* __restrict__ core, float* __restrict__ out) {
    const int tid = blockIdx.x * 256 + threadIdx.x;
    const int p = tid >> 5;
    const int f = tid & 31;

    float s = 0.0f;
#pragma unroll
    for (int k = 0; k < 16; ++k) s += core[k * F_FEAT + f];

    float prod = s;
    const float* planes[3] = {pxy, pyz, pxz};
#pragma unroll
    for (int plane = 0; plane < 3; ++plane) {
        const float cx = coords[((size_t)plane * N_PTS + p) * 2 + 0];
        const float cy = coords[((size_t)plane * N_PTS + p) * 2 + 1];
        const float xf = (cx + 1.0f) * 0.5f * (float)(GRID_ - 1);
        const float yf = (cy + 1.0f) * 0.5f * (float)(GRID_ - 1);
        const float x0f = floorf(xf);
        const float y0f = floorf(yf);
        const float wx = xf - x0f;
        const float wy = yf - y0f;
        int x0 = (int)x0f;
        int y0 = (int)y0f;
        x0 = min(max(x0, 0), GRID_ - 1);
        y0 = min(max(y0, 0), GRID_ - 1);
        const int x1 = min(x0 + 1, GRID_ - 1);
        const int y1 = min(y0 + 1, GRID_ - 1);
        const float* src = planes[plane] + (size_t)f * HW;
        const float v00 = src[y0 * GRID_ + x0];
        const float v01 = src[y0 * GRID_ + x1];
        const float v10 = src[y1 * GRID_ + x0];
        const float v11 = src[y1 * GRID_ + x1];
        prod *= v00 * (1.0f - wx) * (1.0f - wy) + v01 * wx * (1.0f - wy) +
                v10 * (1.0f - wx) * wy + v11 * wx * wy;
    }
    out[(size_t)p * F_FEAT + f] = prod;
}

extern "C" void kernel_launch(void* const* d_in, const int* in_sizes, int n_in,
                              void* d_out, int out_size, void* d_ws,
                              size_t ws_size, hipStream_t stream) {
    const float* coords = (const float*)d_in[0];
    const float* pxy = (const float*)d_in[1];
    const float* pyz = (const float*)d_in[2];
    const float* pxz = (const float*)d_in[3];
    const float* core = (const float*)d_in[4];
    float* out = (float*)d_out;

    // workspace layout (256B-aligned bump allocator)
    size_t off = 0;
    auto alloc = [&off](size_t bytes) {
        size_t o = off;
        off = (off + bytes + 255) & ~(size_t)255;
        return o;
    };
    const size_t off_wsh = alloc(3 * HWF * sizeof(__half));       // fp16 planes
    const size_t off_scale = alloc(32 * sizeof(float));           // scale
    const size_t need_r4 = off;
    const size_t off_cur = alloc(3 * NBINS * sizeof(int));        // cursors
    const size_t off_binned = alloc((size_t)3 * NBINS * BIN_CAP * 16);
    const size_t off_feat = alloc((size_t)3 * N_PTS * F_FEAT * sizeof(__half));
    const size_t need_full = off;

    char* ws = (char*)d_ws;

    if (ws_size >= need_r4) {
        __half* wsh = (__half*)(ws + off_wsh);
        float* scale = (float*)(ws + off_scale);
        td_scale_kernel<<<1, 32, 0, stream>>>(core, scale);
        td_transpose_kernel<<<dim3(GRID_ / 32, GRID_, 3), dim3(32, 8), 0,
                              stream>>>(pxy, pyz, pxz, scale, wsh);
        if (ws_size >= need_full) {
            int* cursor = (int*)(ws + off_cur);
            float4* binned = (float4*)(ws + off_binned);
            f32x4* feat = (f32x4*)(ws + off_feat);
            td_zero_kernel<<<1, 3 * NBINS, 0, stream>>>(cursor);
            td_bin_kernel<<<dim3(N_PTS / 256, 3), 256, 0, stream>>>(
                (const float2*)coords, cursor, binned);
            const int gx = NBINS * BIN_CAP * 4 / 256;
            td_sample_plane_kernel<<<dim3(gx, 3), 256, 0, stream>>>(
                binned, cursor, (const f32x4*)wsh, feat);
            td_combine_kernel<<<N_PTS * 4 / 256, 256, 0, stream>>>(
                (const f32x4*)feat, (f32x4*)out);
        } else {
            td_sample_kernel<<<N_PTS * 4 / 256, 256, 0, stream>>>(
                (const float2*)coords, (const f32x4*)wsh, (f32x4*)out);
        }
    } else {
        td_fallback_kernel<<<N_PTS * 32 / 256, 256, 0, stream>>>(
            coords, pxy, pyz, pxz, core, out);
    }
}

// Round 6
// 378.481 us; speedup vs baseline: 1.9770x; 1.9770x over previous
//
#include <hip/hip_runtime.h>
#include <hip/hip_fp16.h>

#define N_PTS 2097152
#define GRID_ 512
#define F_FEAT 32
#define HW (GRID_ * GRID_)
#define HWF ((size_t)HW * F_FEAT) // elements per transposed plane = 8388608

#define NBINS 64
#define BIN_SHIFT 3     // 8 y-rows per bin -> 256KB fp16 stripe (L2-resident)
#define BIN_CAP 40960   // mean 32768, +45 sigma
#define CUR_STRIDE 32   // cursor padding: 32 ints = 128B per cursor line
#define PTS_PER_BLOCK 1024
#define SEGCAP 64       // per-block per-bin LDS staging capacity (mean 16)
#define BPB 640         // blocks per bin in sample kernels: 40960/64

typedef float f32x4 __attribute__((ext_vector_type(4)));
typedef unsigned long long u64;

// ---------------------------------------------------------------------------
// Kernel 0: scale[f] = sum_k core[k][f]
// ---------------------------------------------------------------------------
__global__ void td_scale_kernel(const float* __restrict__ core,
                                float* __restrict__ scale) {
    int f = threadIdx.x; // 32 threads
    float s = 0.0f;
#pragma unroll
    for (int k = 0; k < 16; ++k) s += core[k * F_FEAT + f];
    scale[f] = s;
}

// ---------------------------------------------------------------------------
// Kernel 1: transpose (F, H, W) f32 -> (H, W, F) fp16. Plane 0 folds scale in.
// ---------------------------------------------------------------------------
__global__ void td_transpose_kernel(const float* __restrict__ pxy,
                                    const float* __restrict__ pyz,
                                    const float* __restrict__ pxz,
                                    const float* __restrict__ scale,
                                    __half* __restrict__ wsh) {
    __shared__ float tile[32][33];
    const int plane = blockIdx.z;
    const float* src = (plane == 0) ? pxy : ((plane == 1) ? pyz : pxz);
    __half* dst = wsh + (size_t)plane * HWF;
    const int y = blockIdx.y;
    const int x0 = blockIdx.x * 32;

    for (int i = threadIdx.y; i < 32; i += 8) {
        tile[i][threadIdx.x] =
            src[(size_t)i * HW + (size_t)y * GRID_ + x0 + threadIdx.x];
    }
    __syncthreads();
    const float sc = (plane == 0) ? scale[threadIdx.x] : 1.0f;
    for (int i = threadIdx.y; i < 32; i += 8) {
        dst[((size_t)(y * GRID_ + x0 + i)) * F_FEAT + threadIdx.x] =
            __float2half(tile[threadIdx.x][i] * sc);
    }
}

// ---------------------------------------------------------------------------
// Kernel 2: zero padded cursors (3*64 entries, stride 32 ints).
// ---------------------------------------------------------------------------
__global__ void td_zero_kernel(int* __restrict__ cursor) {
    for (int i = threadIdx.x; i < 3 * NBINS * CUR_STRIDE; i += 256) cursor[i] = 0;
}

// ---------------------------------------------------------------------------
// Kernel 3: bin points by y-stripe, 8B packed records, LDS-staged runs.
// Record: pid[0:21) | x0[21:30) | y0[30:39) | qwx[39:51) | qwy[51:63)
// ---------------------------------------------------------------------------
__global__ __launch_bounds__(256) void td_bin_kernel(
    const float2* __restrict__ coords, int* __restrict__ cursor,
    u64* __restrict__ recs) {
    __shared__ int lhist[NBINS];
    __shared__ int lbase[NBINS];
    __shared__ u64 lseg[NBINS][SEGCAP]; // 32KB
    const int pl = blockIdx.y;
    const int tid = threadIdx.x;
    const int base_p = blockIdx.x * PTS_PER_BLOCK;
    if (tid < NBINS) lhist[tid] = 0;
    __syncthreads();

    u64 myrec[4];
    int mybin[4], myslot[4];
#pragma unroll
    for (int k = 0; k < 4; ++k) {
        const int p = base_p + k * 256 + tid;
        const float2 c = coords[(size_t)pl * N_PTS + p];
        const float xf = (c.x + 1.0f) * 0.5f * (float)(GRID_ - 1);
        const float yf = (c.y + 1.0f) * 0.5f * (float)(GRID_ - 1);
        const float x0f = floorf(xf);
        const float y0f = floorf(yf);
        const float wx = xf - x0f;
        const float wy = yf - y0f;
        int x0 = min(max((int)x0f, 0), GRID_ - 1);
        int y0 = min(max((int)y0f, 0), GRID_ - 1);
        const int qwx = min(4095, (int)(wx * 4096.0f + 0.5f));
        const int qwy = min(4095, (int)(wy * 4096.0f + 0.5f));
        const int bin = y0 >> BIN_SHIFT;
        myrec[k] = (u64)p | ((u64)x0 << 21) | ((u64)y0 << 30) |
                   ((u64)qwx << 39) | ((u64)qwy << 51);
        mybin[k] = bin;
        myslot[k] = atomicAdd(&lhist[bin], 1);
    }
    __syncthreads();

    if (tid < NBINS) {
        const int cnt = lhist[tid];
        lbase[tid] =
            (cnt > 0) ? atomicAdd(&cursor[(pl * NBINS + tid) * CUR_STRIDE], cnt)
                      : 0;
    }
    // stage in-LDS (grouped by bin)
#pragma unroll
    for (int k = 0; k < 4; ++k)
        if (myslot[k] < SEGCAP) lseg[mybin[k]][myslot[k]] = myrec[k];
    __syncthreads();

    // rare overflow: direct scattered store
#pragma unroll
    for (int k = 0; k < 4; ++k) {
        if (myslot[k] >= SEGCAP) {
            const int gslot = lbase[mybin[k]] + myslot[k];
            if (gslot < BIN_CAP)
                recs[((size_t)pl * NBINS + mybin[k]) * BIN_CAP + gslot] =
                    myrec[k];
        }
    }
    // coalesced flush of staged runs
    for (int b = 0; b < NBINS; ++b) {
        const int cnt = min(lhist[b], SEGCAP);
        const int gb = lbase[b];
        for (int r = tid; r < cnt; r += 256) {
            if (gb + r < BIN_CAP)
                recs[((size_t)pl * NBINS + b) * BIN_CAP + gb + r] = lseg[b][r];
        }
    }
}

// ---------------------------------------------------------------------------
// Shared sampling core: unpack record, gather 4 corners (16B each), interp.
// Returns 8 f32 features for octet fq.
// ---------------------------------------------------------------------------
__device__ __forceinline__ void td_sample_core(u64 r, int fq,
                                               const f32x4* __restrict__ tp,
                                               float* s, int* pid_out) {
    const int pid = (int)(r & 0x1FFFFF);
    const int x0 = (int)((r >> 21) & 511);
    const int y0 = (int)((r >> 30) & 511);
    const float wx = (float)((int)((r >> 39) & 4095)) * (1.0f / 4096.0f);
    const float wy = (float)((int)((r >> 51) & 4095)) * (1.0f / 4096.0f);
    const int x1 = min(x0 + 1, GRID_ - 1);
    const int y1 = min(y0 + 1, GRID_ - 1);

    const f32x4 r00 = tp[(size_t)(y0 * GRID_ + x0) * 4 + fq];
    const f32x4 r01 = tp[(size_t)(y0 * GRID_ + x1) * 4 + fq];
    const f32x4 r10 = tp[(size_t)(y1 * GRID_ + x0) * 4 + fq];
    const f32x4 r11 = tp[(size_t)(y1 * GRID_ + x1) * 4 + fq];

    const float w00 = (1.0f - wx) * (1.0f - wy);
    const float w01 = wx * (1.0f - wy);
    const float w10 = (1.0f - wx) * wy;
    const float w11 = wx * wy;

    const half2* h00 = reinterpret_cast<const half2*>(&r00);
    const half2* h01 = reinterpret_cast<const half2*>(&r01);
    const half2* h10 = reinterpret_cast<const half2*>(&r10);
    const half2* h11 = reinterpret_cast<const half2*>(&r11);
#pragma unroll
    for (int j = 0; j < 4; ++j) {
        const float2 f00 = __half22float2(h00[j]);
        const float2 f01 = __half22float2(h01[j]);
        const float2 f10 = __half22float2(h10[j]);
        const float2 f11 = __half22float2(h11[j]);
        s[2 * j] = f00.x * w00 + f01.x * w01 + f10.x * w10 + f11.x * w11;
        s[2 * j + 1] = f00.y * w00 + f01.y * w01 + f10.y * w10 + f11.y * w11;
    }
    *pid_out = pid;
}

// Swizzle: block i -> xcd (i&7); bins visited so each XCD owns bin%8==xcd.
__device__ __forceinline__ int td_bin_of_block(int i, int* sub) {
    const int xcd = i & 7;
    const int j = i >> 3;
    const int g = j / BPB;
    *sub = j - g * BPB;
    return g * 8 + xcd;
}

// ---------------------------------------------------------------------------
// Kernel 4: sample planes 1 & 2 in bin order; write fp16 octet (16B) into the
// shared 128B feat line: feat[pid] = {plane1: 4x16B | plane2: 4x16B}.
// ---------------------------------------------------------------------------
__global__ __launch_bounds__(256) void td_sample_plane_kernel(
    const u64* __restrict__ recs, const int* __restrict__ cursor,
    const f32x4* __restrict__ ws4, f32x4* __restrict__ featline) {
    const int pl = blockIdx.y + 1;
    int sub;
    const int bin = td_bin_of_block(blockIdx.x, &sub);
    const int slot = sub * 64 + (threadIdx.x >> 2);
    const int fq = threadIdx.x & 3;
    const int cnt = min(cursor[(pl * NBINS + bin) * CUR_STRIDE], BIN_CAP);
    if (slot >= cnt) return;

    const u64 r = recs[((size_t)pl * NBINS + bin) * BIN_CAP + slot];
    float s[8];
    int pid;
    td_sample_core(r, fq, ws4 + (size_t)pl * (HWF / 8), s, &pid);

    union {
        f32x4 v;
        half2 h[4];
    } u;
#pragma unroll
    for (int j = 0; j < 4; ++j) u.h[j] = __floats2half2_rn(s[2 * j], s[2 * j + 1]);
    __builtin_nontemporal_store(
        u.v, &featline[(size_t)pid * 8 + (pl - 1) * 4 + fq]);
}

// ---------------------------------------------------------------------------
// Kernel 5: sample plane 0 (scale folded) in bin order; read the point's
// 128B feat line; multiply; write out[pid] (128B full line, NT).
// ---------------------------------------------------------------------------
__global__ __launch_bounds__(256) void td_sample_combine_kernel(
    const u64* __restrict__ recs, const int* __restrict__ cursor,
    const f32x4* __restrict__ ws4, const f32x4* __restrict__ featline,
    f32x4* __restrict__ out) {
    int sub;
    const int bin = td_bin_of_block(blockIdx.x, &sub);
    const int slot = sub * 64 + (threadIdx.x >> 2);
    const int fq = threadIdx.x & 3;
    const int cnt = min(cursor[bin * CUR_STRIDE], BIN_CAP);
    if (slot >= cnt) return;

    const u64 r = recs[(size_t)bin * BIN_CAP + slot];
    float s[8];
    int pid;
    td_sample_core(r, fq, ws4, s, &pid);

    union {
        f32x4 v;
        half2 h[4];
    } f1, f2;
    f1.v = featline[(size_t)pid * 8 + fq];
    f2.v = featline[(size_t)pid * 8 + 4 + fq];

    f32x4 o0, o1;
    float rr[8];
#pragma unroll
    for (int j = 0; j < 4; ++j) {
        const float2 a = __half22float2(f1.h[j]);
        const float2 b = __half22float2(f2.h[j]);
        rr[2 * j] = s[2 * j] * a.x * b.x;
        rr[2 * j + 1] = s[2 * j + 1] * a.y * b.y;
    }
    o0.x = rr[0]; o0.y = rr[1]; o0.z = rr[2]; o0.w = rr[3];
    o1.x = rr[4]; o1.y = rr[5]; o1.z = rr[6]; o1.w = rr[7];
    __builtin_nontemporal_store(o0, &out[(size_t)pid * 8 + fq * 2]);
    __builtin_nontemporal_store(o1, &out[(size_t)pid * 8 + fq * 2 + 1]);
}

// ---------------------------------------------------------------------------
// Tier-2: fused random-gather sampling (needs only fp16 planes).
// ---------------------------------------------------------------------------
__global__ __launch_bounds__(256) void td_sample_kernel(
    const float2* __restrict__ coords, const f32x4* __restrict__ ws4,
    f32x4* __restrict__ out) {
    const int tid = blockIdx.x * 256 + threadIdx.x;
    const int p = tid >> 2;
    const int fq = tid & 3;

    const float2 c0 = coords[p];
    const float2 c1 = coords[N_PTS + p];
    const float2 c2 = coords[2 * N_PTS + p];

    size_t idx[3][4];
    float w[3][4];
    const float2 cc[3] = {c0, c1, c2};
#pragma unroll
    for (int pl = 0; pl < 3; ++pl) {
        const float xf = (cc[pl].x + 1.0f) * 0.5f * (float)(GRID_ - 1);
        const float yf = (cc[pl].y + 1.0f) * 0.5f * (float)(GRID_ - 1);
        const float x0f = floorf(xf);
        const float y0f = floorf(yf);
        const float wx = xf - x0f;
        const float wy = yf - y0f;
        int x0 = min(max((int)x0f, 0), GRID_ - 1);
        int y0 = min(max((int)y0f, 0), GRID_ - 1);
        const int x1 = min(x0 + 1, GRID_ - 1);
        const int y1 = min(y0 + 1, GRID_ - 1);
        const size_t base = (size_t)pl * (HWF / 8);
        idx[pl][0] = base + (size_t)(y0 * GRID_ + x0) * 4 + fq;
        idx[pl][1] = base + (size_t)(y0 * GRID_ + x1) * 4 + fq;
        idx[pl][2] = base + (size_t)(y1 * GRID_ + x0) * 4 + fq;
        idx[pl][3] = base + (size_t)(y1 * GRID_ + x1) * 4 + fq;
        w[pl][0] = (1.0f - wx) * (1.0f - wy);
        w[pl][1] = wx * (1.0f - wy);
        w[pl][2] = (1.0f - wx) * wy;
        w[pl][3] = wx * wy;
    }

    f32x4 v[3][4];
#pragma unroll
    for (int pl = 0; pl < 3; ++pl)
#pragma unroll
        for (int cnr = 0; cnr < 4; ++cnr) v[pl][cnr] = ws4[idx[pl][cnr]];

    float prod[8];
#pragma unroll
    for (int j = 0; j < 8; ++j) prod[j] = 1.0f;
#pragma unroll
    for (int pl = 0; pl < 3; ++pl) {
        const half2* h0 = reinterpret_cast<const half2*>(&v[pl][0]);
        const half2* h1 = reinterpret_cast<const half2*>(&v[pl][1]);
        const half2* h2 = reinterpret_cast<const half2*>(&v[pl][2]);
        const half2* h3 = reinterpret_cast<const half2*>(&v[pl][3]);
#pragma unroll
        for (int j = 0; j < 4; ++j) {
            const float2 f00 = __half22float2(h0[j]);
            const float2 f01 = __half22float2(h1[j]);
            const float2 f10 = __half22float2(h2[j]);
            const float2 f11 = __half22float2(h3[j]);
            prod[2 * j] *= f00.x * w[pl][0] + f01.x * w[pl][1] +
                           f10.x * w[pl][2] + f11.x * w[pl][3];
            prod[2 * j + 1] *= f00.y * w[pl][0] + f01.y * w[pl][1] +
                               f10.y * w[pl][2] + f11.y * w[pl][3];
        }
    }

    f32x4 o0, o1;
    o0.x = prod[0]; o0.y = prod[1]; o0.z = prod[2]; o0.w = prod[3];
    o1.x = prod[4]; o1.y = prod[5]; o1.z = prod[6]; o1.w = prod[7];
    __builtin_nontemporal_store(o0, &out[(size_t)tid * 2]);
    __builtin_nontemporal_store(o1, &out[(size_t)tid * 2 + 1]);
}

// ---------------------------------------------------------------------------
// Tier-3: no workspace.
// ---------------------------------------------------------------------------
__global__ __launch_bounds__(256) void td_fallback_kernel(
    const float* __restrict__ coords, const float* __restrict__ pxy,
    const float* __restrict__ pyz, const float* __restrict__ pxz,
    const float* __restrict__ core, float* __restrict__ out) {
    const int tid = blockIdx.x * 256 + threadIdx.x;
    const int p = tid >> 5;
    const int f = tid & 31;

    float s = 0.0f;
#pragma unroll
    for (int k = 0; k < 16; ++k) s += core[k * F_FEAT + f];

    float prod = s;
    const float* planes[3] = {pxy, pyz, pxz};
#pragma unroll
    for (int plane = 0; plane < 3; ++plane) {
        const float cx = coords[((size_t)plane * N_PTS + p) * 2 + 0];
        const float cy = coords[((size_t)plane * N_PTS + p) * 2 + 1];
        const float xf = (cx + 1.0f) * 0.5f * (float)(GRID_ - 1);
        const float yf = (cy + 1.0f) * 0.5f * (float)(GRID_ - 1);
        const float x0f = floorf(xf);
        const float y0f = floorf(yf);
        const float wx = xf - x0f;
        const float wy = yf - y0f;
        int x0 = min(max((int)x0f, 0), GRID_ - 1);
        int y0 = min(max((int)y0f, 0), GRID_ - 1);
        const int x1 = min(x0 + 1, GRID_ - 1);
        const int y1 = min(y0 + 1, GRID_ - 1);
        const float* src = planes[plane] + (size_t)f * HW;
        const float v00 = src[y0 * GRID_ + x0];
        const float v01 = src[y0 * GRID_ + x1];
        const float v10 = src[y1 * GRID_ + x0];
        const float v11 = src[y1 * GRID_ + x1];
        prod *= v00 * (1.0f - wx) * (1.0f - wy) + v01 * wx * (1.0f - wy) +
                v10 * (1.0f - wx) * wy + v11 * wx * wy;
    }
    out[(size_t)p * F_FEAT + f] = prod;
}

extern "C" void kernel_launch(void* const* d_in, const int* in_sizes, int n_in,
                              void* d_out, int out_size, void* d_ws,
                              size_t ws_size, hipStream_t stream) {
    const float* coords = (const float*)d_in[0];
    const float* pxy = (const float*)d_in[1];
    const float* pyz = (const float*)d_in[2];
    const float* pxz = (const float*)d_in[3];
    const float* core = (const float*)d_in[4];
    float* out = (float*)d_out;

    size_t off = 0;
    auto alloc = [&off](size_t bytes) {
        size_t o = off;
        off = (off + bytes + 255) & ~(size_t)255;
        return o;
    };
    const size_t off_wsh = alloc(3 * HWF * sizeof(__half)); // fp16 planes
    const size_t off_scale = alloc(32 * sizeof(float));
    const size_t need_r4 = off;
    const size_t off_cur = alloc((size_t)3 * NBINS * CUR_STRIDE * sizeof(int));
    const size_t off_recs = alloc((size_t)3 * NBINS * BIN_CAP * sizeof(u64));
    const size_t off_feat = alloc((size_t)N_PTS * 128); // 128B feat line / pt
    const size_t need_full = off;

    char* ws = (char*)d_ws;

    if (ws_size >= need_r4) {
        __half* wsh = (__half*)(ws + off_wsh);
        float* scale = (float*)(ws + off_scale);
        td_scale_kernel<<<1, 32, 0, stream>>>(core, scale);
        td_transpose_kernel<<<dim3(GRID_ / 32, GRID_, 3), dim3(32, 8), 0,
                              stream>>>(pxy, pyz, pxz, scale, wsh);
        if (ws_size >= need_full) {
            int* cursor = (int*)(ws + off_cur);
            u64* recs = (u64*)(ws + off_recs);
            f32x4* featline = (f32x4*)(ws + off_feat);
            td_zero_kernel<<<1, 256, 0, stream>>>(cursor);
            td_bin_kernel<<<dim3(N_PTS / PTS_PER_BLOCK, 3), 256, 0, stream>>>(
                (const float2*)coords, cursor, recs);
            td_sample_plane_kernel<<<dim3(NBINS * BPB, 2), 256, 0, stream>>>(
                recs, cursor, (const f32x4*)wsh, featline);
            td_sample_combine_kernel<<<NBINS * BPB, 256, 0, stream>>>(
                recs, cursor, (const f32x4*)wsh, (const f32x4*)featline,
                (f32x4*)out);
        } else {
            td_sample_kernel<<<N_PTS * 4 / 256, 256, 0, stream>>>(
                (const float2*)coords, (const f32x4*)wsh, (f32x4*)out);
        }
    } else {
        td_fallback_kernel<<<N_PTS * 32 / 256, 256, 0, stream>>>(
            coords, pxy, pyz, pxz, core, out);
    }
}